// Round 8
// baseline (320.442 us; speedup 1.0000x reference)
//
#include <hip/hip_runtime.h>
#include <hip/hip_bf16.h>
#include <math.h>

// Top-p + exponential-minimum sampling.
//   - sort by prob desc == sort by logit desc
//   - kept set == { (l,idx) >= (l_cut,idx_cut) } via descending exp-mass crossing
//   - argmin -log(xi)/p == argmin [ key[v] - l ],  key = log(-log(xi))
// Math identical to round-7 (passed absmax=0): count-histogram over 4096 logit
// bins, scan with count[b]*exp(bin center), exact within-bin resolution via
// sorted bin-B tokens + fp64 crossing, candidate pre-filter {key < -3} with
// runtime proof (bestScore < -3 - lmax) and exact fallback.
// Structure (restructured for occupancy/MLP; r7 was latency-bound at 42% occ):
//   K0: key[v] + candidate compaction per 1024-token chunk.
//   K1: 8 blocks/row x 256 thr: batched sweep, LDS u32 count hist (ds_add),
//       per-thread lmax; partial hist -> ws.phist (coalesced), lmax -> ws.
//   K2: 1 block/row: sum 8 partials, wave-0 scan -> bin B, cumAbove, target;
//       batched L3-hot regather of bin-B tokens; 1-barrier rank-sort; fp64
//       crossing -> (l_cut, idx_cut); candidate argmin + proof; fallback.
//   KD: fill out with NEG_FILL, POS_FILL at winner.

constexpr int   NBINS     = 4096;
constexpr float BIN_MIN   = -8.0f;
constexpr float BIN_SCALE = 256.0f;
constexpr float BIN_OFF   = 2048.0f;       // -BIN_MIN*BIN_SCALE
constexpr float BIN_W     = 1.0f / 256.0f;
constexpr int   BINB_CAP  = 512;
constexpr int   MAXC      = 96;            // candidate slots per 1024-token chunk
constexpr float CAND_THR  = -3.0f;
constexpr float NEG_FILL  = -100000.0f;
constexpr float POS_FILL  =  100000.0f;
constexpr float TOPP      = 0.9f;
constexpr int   BPR_FILL  = 32;
constexpr int   SLICES    = 8;

struct Ws {
    float*    key;      // [V]
    unsigned* candIdx;  // [nchunk*MAXC]
    float*    candKey;  // [nchunk*MAXC]  (INF sentinel padding)
    int*      candCnt;  // [nchunk]
    unsigned* phist;    // [B*SLICES*NBINS]
    float*    lmaxArr;  // [B*SLICES]
    unsigned long long* winner; // [B]
};

__device__ __forceinline__ unsigned sortable(float f) {
    unsigned u = __float_as_uint(f);
    return (u & 0x80000000u) ? ~u : (u | 0x80000000u);
}
__device__ __forceinline__ int binOf(float l) {
    int b = (int)fmaf(l, BIN_SCALE, BIN_OFF);
    return min(max(b, 0), NBINS - 1);
}

// ---------------- K0: keys + candidate compaction ----------------
__global__ __launch_bounds__(256)
void k0_keys(const float4* __restrict__ xi4, float* __restrict__ key,
             unsigned* __restrict__ candIdx, float* __restrict__ candKey,
             int* __restrict__ candCnt, int V4)
{
    __shared__ int cnt;
    __shared__ unsigned sIdx[MAXC];
    __shared__ float    sKey[MAXC];
    if (threadIdx.x == 0) cnt = 0;
    __syncthreads();

    const int f = blockIdx.x * 256 + threadIdx.x;
    if (f < V4) {
        float4 x = xi4[f];
        float kv[4];
        kv[0] = __logf(-__logf(x.x));
        kv[1] = __logf(-__logf(x.y));
        kv[2] = __logf(-__logf(x.z));
        kv[3] = __logf(-__logf(x.w));
        reinterpret_cast<float4*>(key)[f] = make_float4(kv[0], kv[1], kv[2], kv[3]);
        #pragma unroll
        for (int c = 0; c < 4; ++c) {
            if (kv[c] < CAND_THR) {
                int p = atomicAdd(&cnt, 1);
                if (p < MAXC) { sIdx[p] = (unsigned)(f * 4 + c); sKey[p] = kv[c]; }
            }
        }
    }
    __syncthreads();
    const int base = blockIdx.x * MAXC;
    const int n = min(cnt, MAXC);
    for (int i = threadIdx.x; i < MAXC; i += 256) {
        candIdx[base + i] = (i < n) ? sIdx[i] : 0u;
        candKey[base + i] = (i < n) ? sKey[i] : INFINITY;
    }
    if (threadIdx.x == 0) candCnt[blockIdx.x] = cnt;
}

// ---------------- K1: sliced count-histogram sweep ----------------
__global__ __launch_bounds__(256, 8)
void k1_sweep(const float* __restrict__ logits, unsigned* __restrict__ phist,
              float* __restrict__ lmaxArr, int V)
{
    const int row = blockIdx.x / SLICES;
    const int sl  = blockIdx.x % SLICES;
    const int n4  = V >> 2;
    const int per = n4 / SLICES;                 // 4000 for V=128000
    const float4* p4 = reinterpret_cast<const float4*>(logits + (size_t)row * V) + sl * per;

    __shared__ unsigned lh[NBINS];
    __shared__ float wrf[4];
    for (int i = threadIdx.x; i < NBINS; i += 256) lh[i] = 0u;
    __syncthreads();

    float lmax = -INFINITY;
    for (int base = 0; base < per; base += 1024) {
        float4 r[4];
        int    j[4];
        #pragma unroll
        for (int u = 0; u < 4; ++u) {
            j[u] = base + u * 256 + threadIdx.x;
            if (j[u] < per) r[u] = p4[j[u]];
        }
        #pragma unroll
        for (int u = 0; u < 4; ++u) {
            if (j[u] < per) {
                float lv[4] = {r[u].x, r[u].y, r[u].z, r[u].w};
                #pragma unroll
                for (int c = 0; c < 4; ++c) {
                    atomicAdd(&lh[binOf(lv[c])], 1u);
                    lmax = fmaxf(lmax, lv[c]);
                }
            }
        }
    }
    __syncthreads();

    // coalesced partial-hist writeout
    unsigned* dst = phist + ((size_t)row * SLICES + sl) * NBINS;
    uint4* d4 = reinterpret_cast<uint4*>(dst);
    const uint4* s4 = reinterpret_cast<const uint4*>(lh);
    for (int i = threadIdx.x; i < NBINS / 4; i += 256) d4[i] = s4[i];

    // lmax block reduce
    for (int off = 32; off >= 1; off >>= 1)
        lmax = fmaxf(lmax, __shfl_down(lmax, off));
    if ((threadIdx.x & 63) == 0) wrf[threadIdx.x >> 6] = lmax;
    __syncthreads();
    if (threadIdx.x == 0) {
        float m = fmaxf(fmaxf(wrf[0], wrf[1]), fmaxf(wrf[2], wrf[3]));
        lmaxArr[row * SLICES + sl] = m;
    }
}

// ---------------- descending scan helper (wave 0) -----------
__device__ __forceinline__ void scan_bins(const unsigned* lh, int lane,
                                          int& candBin, double& candS, double& target)
{
    const int hi = NBINS - 1 - (lane << 6);
    double seg = 0.0;
    for (int k = 0; k < 64; ++k) {
        int b = hi - k;
        seg += (double)lh[b] * (double)__expf(fmaf((float)b + 0.5f, BIN_W, BIN_MIN));
    }
    double v = seg;
    for (int off = 1; off < 64; off <<= 1) {
        double u = __shfl_up(v, off);
        if (lane >= off) v += u;
    }
    double excl = v - seg;
    double total = __shfl(v, 63);
    target = TOPP * total;

    candBin = -1; candS = 0.0;
    double cum = excl;
    for (int k = 0; k < 64; ++k) {
        int b = hi - k;
        double h = (double)lh[b] * (double)__expf(fmaf((float)b + 0.5f, BIN_W, BIN_MIN));
        if (candBin < 0 && cum + h >= target) { candBin = b; candS = cum; }
        cum += h;
    }
    for (int off = 32; off >= 1; off >>= 1) {
        int    ob = __shfl_xor(candBin, off);
        double os = __shfl_xor(candS, off);
        if (ob > candBin) { candBin = ob; candS = os; }
    }
}

// ---------------- K2: resolve per row ----------------
__global__ __launch_bounds__(1024)
void k2_resolve(const float* __restrict__ logits, const float* __restrict__ key,
                const unsigned* __restrict__ phist, const float* __restrict__ lmaxArr,
                const unsigned* __restrict__ candIdx, const float* __restrict__ candKey,
                const int* __restrict__ candCnt,
                unsigned long long* __restrict__ winner,
                int V, int nchunk, int nslots)
{
    const int row = blockIdx.x;
    const int tid = threadIdx.x;
    const int n4  = V >> 2;
    const float* rowp = logits + (size_t)row * V;
    const float4* p4 = reinterpret_cast<const float4*>(rowp);

    __shared__ unsigned lh[NBINS];
    __shared__ float  s_bl[BINB_CAP];
    __shared__ int    s_bi[BINB_CAP];
    __shared__ float  s_sl[BINB_CAP];
    __shared__ int    s_si[BINB_CAP];
    __shared__ double s_be[BINB_CAP];
    __shared__ unsigned long long wrd[16];
    __shared__ int   sB2, sB, sNeedFull;
    __shared__ float sLcut;
    __shared__ int   sIcut;
    __shared__ double sCumAbove, sTarget;
    __shared__ unsigned long long sBest;

    // sum 8 partial hists
    const unsigned* ph = phist + (size_t)row * SLICES * NBINS;
    for (int i = tid; i < NBINS; i += 1024) {
        unsigned s = 0;
        #pragma unroll
        for (int k = 0; k < SLICES; ++k) s += ph[k * NBINS + i];
        lh[i] = s;
    }
    if (tid == 0) { sB2 = 0; sNeedFull = 0; }
    __syncthreads();
    if (tid < nchunk && candCnt[tid] > MAXC) atomicOr(&sNeedFull, 1);

    // scan
    if (tid < 64) {
        int b; double cs, tg;
        scan_bins(lh, tid, b, cs, tg);
        if (tid == 0) { sB = b; sCumAbove = cs; sTarget = tg; }
    }
    __syncthreads();
    const int B = sB;

    // regather bin-B tokens (L3-hot re-read, batched)
    for (int base = 0; base < n4; base += 4096) {
        float4 r[4];
        int    j[4];
        #pragma unroll
        for (int u = 0; u < 4; ++u) {
            j[u] = base + u * 1024 + tid;
            if (j[u] < n4) r[u] = p4[j[u]];
        }
        #pragma unroll
        for (int u = 0; u < 4; ++u) {
            if (j[u] < n4) {
                float lv[4] = {r[u].x, r[u].y, r[u].z, r[u].w};
                #pragma unroll
                for (int c = 0; c < 4; ++c) {
                    if (binOf(lv[c]) == B) {
                        int q = atomicAdd(&sB2, 1);
                        if (q < BINB_CAP) { s_bl[q] = lv[c]; s_bi[q] = j[u] * 4 + c; }
                    }
                }
            }
        }
    }
    __syncthreads();
    const int nB = min(sB2, BINB_CAP);

    // rank-sort (desc by l, idx asc on ties) — one barrier
    for (int i = tid; i < nB; i += 1024) {
        float li = s_bl[i]; int ii = s_bi[i];
        int r = 0;
        for (int j = 0; j < nB; ++j) {
            float lj = s_bl[j]; int ij = s_bi[j];
            r += (lj > li) || (lj == li && ij < ii);
        }
        s_sl[r] = li; s_si[r] = ii;
    }
    __syncthreads();

    // fp64 crossing -> (l_cut, idx_cut)
    for (int i = tid; i < nB; i += 1024) s_be[i] = exp((double)s_sl[i]);
    __syncthreads();
    if (tid == 0) {
        double cum = sCumAbove, target = sTarget;
        int m = nB;
        for (int k = 0; k < nB; ++k) {
            cum += s_be[k];
            if (cum >= target) { m = k + 1; break; }
        }
        m = max(m, 1);
        if (nB == 0) { sNeedFull = 1; sLcut = (float)B * BIN_W + BIN_MIN; sIcut = 0x7fffffff; }
        else { sLcut = s_sl[m - 1]; sIcut = s_si[m - 1]; }
    }
    __syncthreads();
    const float lcut = sLcut;
    const int   icut = sIcut;

    // candidate argmin over kept
    unsigned long long best = ~0ull;
    for (int s = tid; s < nslots; s += 1024) {
        unsigned idx = candIdx[s];
        float ck = candKey[s];
        float l = rowp[idx];
        bool kept = (l > lcut) || (l == lcut && (int)idx <= icut);
        if (kept) {
            unsigned long long pack =
                ((unsigned long long)sortable(ck - l) << 32) | idx;
            best = pack < best ? pack : best;
        }
    }
    for (int off = 32; off >= 1; off >>= 1) {
        unsigned long long o = __shfl_down(best, off);
        best = o < best ? o : best;
    }
    if ((tid & 63) == 0) wrd[tid >> 6] = best;
    __syncthreads();
    if (tid == 0) {
        unsigned long long b = wrd[0];
        for (int w = 1; w < 16; ++w) b = wrd[w] < b ? wrd[w] : b;
        sBest = b;
        float lmax = -INFINITY;
        for (int k = 0; k < SLICES; ++k) lmax = fmaxf(lmax, lmaxArr[row * SLICES + k]);
        unsigned bound = sortable(CAND_THR - lmax);
        if (!((unsigned)(b >> 32) < bound)) sNeedFull = 1;
    }
    __syncthreads();

    // exact fallback (statistically never taken)
    if (sNeedFull) {
        for (int j = tid; j < V; j += 1024) {
            float l = rowp[j];
            bool kept = (l > lcut) || (l == lcut && j <= icut);
            if (kept) {
                unsigned long long pack =
                    ((unsigned long long)sortable(key[j] - l) << 32) | (unsigned)j;
                best = pack < best ? pack : best;
            }
        }
        for (int off = 32; off >= 1; off >>= 1) {
            unsigned long long o = __shfl_down(best, off);
            best = o < best ? o : best;
        }
        if ((tid & 63) == 0) wrd[tid >> 6] = best;
        __syncthreads();
        if (tid == 0) {
            unsigned long long b = sBest;
            for (int w = 0; w < 16; ++w) b = wrd[w] < b ? wrd[w] : b;
            sBest = b;
        }
        __syncthreads();
    }

    if (tid == 0) winner[row] = sBest;
}

// ---------------- KD: fill output ----------------
__global__ __launch_bounds__(256)
void kd_fill(float* __restrict__ out,
             const unsigned long long* __restrict__ winner, int V)
{
    const int row = blockIdx.x / BPR_FILL;
    const int seg = blockIdx.x % BPR_FILL;
    const int n4  = V >> 2;
    const int per = n4 / BPR_FILL;
    const int start = seg * per;
    const int end = (seg == BPR_FILL - 1) ? n4 : start + per;
    float4* o4 = reinterpret_cast<float4*>(out + (size_t)row * V);

    const unsigned win = (unsigned)(winner[row] & 0xffffffffu);
    const int winj = (int)(win >> 2);

    const float4 nf = make_float4(NEG_FILL, NEG_FILL, NEG_FILL, NEG_FILL);
    for (int j = start + threadIdx.x; j < end; j += 256) {
        float4 v = nf;
        if (j == winj) {
            float ov[4] = {v.x, v.y, v.z, v.w};
            ov[win & 3] = POS_FILL;
            v = make_float4(ov[0], ov[1], ov[2], ov[3]);
        }
        o4[j] = v;
    }
}

extern "C" void kernel_launch(void* const* d_in, const int* in_sizes, int n_in,
                              void* d_out, int out_size, void* d_ws, size_t ws_size,
                              hipStream_t stream) {
    // d_in[0] = input_ids (int64, unused)
    // d_in[1] = logits f32 [B, V]
    // d_in[2] = xi     f32 [V]
    const float* logits = (const float*)d_in[1];
    const float* xi     = (const float*)d_in[2];
    float*       out    = (float*)d_out;
    const int V = in_sizes[2];
    const int B = in_sizes[1] / V;
    const int V4 = V / 4;
    const int nchunk = (V + 1023) / 1024;
    const int nslots = nchunk * MAXC;

    char* w = (char*)d_ws;
    size_t off = 0;
    Ws ws;
    ws.key     = (float*)(w + off);    off += (size_t)V * sizeof(float);
    off = (off + 255) & ~(size_t)255;
    ws.candIdx = (unsigned*)(w + off); off += (size_t)nslots * sizeof(unsigned);
    ws.candKey = (float*)(w + off);    off += (size_t)nslots * sizeof(float);
    ws.candCnt = (int*)(w + off);      off += (size_t)nchunk * sizeof(int);
    off = (off + 255) & ~(size_t)255;
    ws.phist   = (unsigned*)(w + off); off += (size_t)B * SLICES * NBINS * sizeof(unsigned);
    ws.lmaxArr = (float*)(w + off);    off += (size_t)B * SLICES * sizeof(float);
    off = (off + 255) & ~(size_t)255;
    ws.winner  = (unsigned long long*)(w + off); off += (size_t)B * sizeof(unsigned long long);

    k0_keys   <<<(V4 + 255) / 256, 256, 0, stream>>>((const float4*)xi, ws.key,
                                                     ws.candIdx, ws.candKey, ws.candCnt, V4);
    k1_sweep  <<<B * SLICES, 256, 0, stream>>>(logits, ws.phist, ws.lmaxArr, V);
    k2_resolve<<<B, 1024, 0, stream>>>(logits, ws.key, ws.phist, ws.lmaxArr,
                                       ws.candIdx, ws.candKey, ws.candCnt,
                                       ws.winner, V, nchunk, nslots);
    kd_fill   <<<B * BPR_FILL, 256, 0, stream>>>(out, ws.winner, V);
}